// Round 4
// baseline (388.094 us; speedup 1.0000x reference)
//
#include <hip/hip_runtime.h>

// ---------- common types ----------
typedef float  f32x4  __attribute__((ext_vector_type(4)));
typedef short  bf16x8 __attribute__((ext_vector_type(8)));

#define MFMA16(a, b, c) __builtin_amdgcn_mfma_f32_16x16x32_bf16((a), (b), (c), 0, 0, 0)

__device__ __forceinline__ short f2bf(float f) {
    union { float f; unsigned u; } a; a.f = f;
    unsigned r = a.u + 0x7fffu + ((a.u >> 16) & 1u);  // RNE
    return (short)(r >> 16);
}

// sizes
#define Bb   8
#define Nn   1024
#define DIM  768
#define HH   12
#define HD   64
#define INNER 768
#define SCALE 0.125f

// ---------- prep kernels ----------
__global__ void cast_to_bf16(const float* __restrict__ in, short* __restrict__ out, int n4) {
    int i = blockIdx.x * 256 + threadIdx.x;
    if (i >= n4) return;
    float4 f = reinterpret_cast<const float4*>(in)[i];
    unsigned lo = (unsigned)(unsigned short)f2bf(f.x) | ((unsigned)(unsigned short)f2bf(f.y) << 16);
    unsigned hi = (unsigned)(unsigned short)f2bf(f.z) | ((unsigned)(unsigned short)f2bf(f.w) << 16);
    reinterpret_cast<uint2*>(out)[i] = make_uint2(lo, hi);
}

// wt[c][k] = w[k][c]; w is [rows=K][cols], wt is [cols][K]
__global__ void transpose_cast(const float* __restrict__ w, short* __restrict__ wt,
                               int rows, int cols) {
    int idx = blockIdx.x * 256 + threadIdx.x;
    if (idx >= rows * cols) return;
    int c = idx / rows;
    int k = idx - c * rows;
    wt[idx] = f2bf(w[k * cols + c]);
}

// ---------- GEMM: C[M,N] = A[M,K] @ Bt[N,K]^T ----------
template <int MODE>
__global__ __launch_bounds__(256, 2)
void gemm128(const short* __restrict__ A, const short* __restrict__ Bt, int K,
             short* __restrict__ qb, short* __restrict__ kb, short* __restrict__ vtb,
             float* __restrict__ outp, const float* __restrict__ bias) {
    __shared__ __align__(16) short As[128 * 40];
    __shared__ __align__(16) short Bs[128 * 40];

    const int tid  = threadIdx.x;
    const int lane = tid & 63, wv = tid >> 6;
    const int wrow = wv >> 1, wcol = wv & 1;
    const int quad = lane >> 4, l16 = lane & 15;
    const int m0 = blockIdx.y * 128, n0 = blockIdx.x * 128;

    const int srow = tid >> 1;
    const int soff = (tid & 1) * 16;

    f32x4 acc[4][4];
#pragma unroll
    for (int i = 0; i < 4; i++)
#pragma unroll
        for (int j = 0; j < 4; j++) acc[i][j] = (f32x4){0.f, 0.f, 0.f, 0.f};

    for (int kc = 0; kc < K; kc += 32) {
        const uint4 a0 = *reinterpret_cast<const uint4*>(A + (size_t)(m0 + srow) * K + kc + soff);
        const uint4 a1 = *reinterpret_cast<const uint4*>(A + (size_t)(m0 + srow) * K + kc + soff + 8);
        const uint4 b0 = *reinterpret_cast<const uint4*>(Bt + (size_t)(n0 + srow) * K + kc + soff);
        const uint4 b1 = *reinterpret_cast<const uint4*>(Bt + (size_t)(n0 + srow) * K + kc + soff + 8);
        __syncthreads();
        *reinterpret_cast<uint4*>(&As[srow * 40 + soff])     = a0;
        *reinterpret_cast<uint4*>(&As[srow * 40 + soff + 8]) = a1;
        *reinterpret_cast<uint4*>(&Bs[srow * 40 + soff])     = b0;
        *reinterpret_cast<uint4*>(&Bs[srow * 40 + soff + 8]) = b1;
        __syncthreads();

        bf16x8 af[4], bfr[4];
#pragma unroll
        for (int t = 0; t < 4; t++)
            af[t] = *reinterpret_cast<bf16x8*>(&As[(wrow * 64 + t * 16 + l16) * 40 + quad * 8]);
#pragma unroll
        for (int t = 0; t < 4; t++)
            bfr[t] = *reinterpret_cast<bf16x8*>(&Bs[(wcol * 64 + t * 16 + l16) * 40 + quad * 8]);
#pragma unroll
        for (int rt = 0; rt < 4; rt++)
#pragma unroll
            for (int ct = 0; ct < 4; ct++)
                acc[rt][ct] = MFMA16(af[rt], bfr[ct], acc[rt][ct]);
    }

    // epilogue: C/D layout col=lane&15, row=quad*4+reg
#pragma unroll
    for (int rt = 0; rt < 4; rt++) {
#pragma unroll
        for (int ct = 0; ct < 4; ct++) {
            const int c = n0 + wcol * 64 + ct * 16 + l16;
#pragma unroll
            for (int reg = 0; reg < 4; reg++) {
                const int r = m0 + wrow * 64 + rt * 16 + quad * 4 + reg;
                const float v = acc[rt][ct][reg];
                if (MODE == 0) {
                    const int b = r >> 10, n = r & 1023;
                    const int which = (c >= 1536) ? 2 : (c >= 768 ? 1 : 0);
                    const int cc = c - which * 768;
                    const int h = cc >> 6, d = cc & 63;
                    const int bh = b * HH + h;
                    const short bv = f2bf(v);
                    if (which == 0)      qb[(bh << 16) + (n << 6) + d] = bv;
                    else if (which == 1) kb[(bh << 16) + (n << 6) + d] = bv;
                    else                 vtb[(bh << 16) + (d << 10) + n] = bv;
                } else {
                    outp[(size_t)r * 768 + c] = v + bias[c];
                }
            }
        }
    }
}

// ---------- single-pass fused attention ----------
// softmax over HEADS is local per (b,n,m): with one wave computing S for all
// 12 heads at the same (n16,m16) tile, every head's S sits at the same
// (lane,reg) C-layout position -> softmax is pure per-lane register math.
// Block = (b, n16): 512 blocks (b = bid&7 for XCD L2 locality; K+V per b =
// 3 MB fits the 4 MB XCD L2). Per m64-iter: wave w owns m-slice m0+16w for
// QK/softmax and d-chunk 16w for PV. LDS used ONLY for the P C->A transform.
__global__ __launch_bounds__(256, 2)
void attn_fused2(const short* __restrict__ qb, const short* __restrict__ kb,
                 const short* __restrict__ vtb, short* __restrict__ attn_out) {
    __shared__ __align__(16) short pP[12 * 16 * 70 + 8];  // [h][n16][m64], stride 70

    const int tid = threadIdx.x, lane = tid & 63, wv = tid >> 6;
    const int quad = lane >> 4, l16 = lane & 15;
    const int b = blockIdx.x & 7;
    const int n0 = (blockIdx.x >> 3) << 4;

    // Q A-frags for all 12 heads (row=l16 -> n, k=quad*8+j -> d), held in regs
    bf16x8 aq[12][2];
#pragma unroll
    for (int h = 0; h < 12; h++) {
        const short* qp = qb + ((b * HH + h) << 16) + ((n0 + l16) << 6) + quad * 8;
        aq[h][0] = *reinterpret_cast<const bf16x8*>(qp);
        aq[h][1] = *reinterpret_cast<const bf16x8*>(qp + 32);
    }

    const f32x4 z = (f32x4){0.f, 0.f, 0.f, 0.f};
    f32x4 O[12];
#pragma unroll
    for (int h = 0; h < 12; h++) O[h] = z;

    for (int m0 = 0; m0 < Nn; m0 += 64) {
        const int mw = m0 + wv * 16;  // this wave's m16 slice

        // --- S for all 12 heads at (n16, mw16); K-frags from L2 ---
        f32x4 p[12];
#pragma unroll
        for (int h = 0; h < 12; h++) {
            const short* kp = kb + ((b * HH + h) << 16) + ((mw + l16) << 6) + quad * 8;
            const bf16x8 k0 = *reinterpret_cast<const bf16x8*>(kp);
            const bf16x8 k1 = *reinterpret_cast<const bf16x8*>(kp + 32);
            f32x4 s = MFMA16(aq[h][0], k0, z);
            p[h] = MFMA16(aq[h][1], k1, s);
        }

        // --- per-lane softmax over heads (no max-sub: |s*scale| ~ N(0,1)) ---
#pragma unroll
        for (int reg = 0; reg < 4; reg++) {
            float den = 0.f;
#pragma unroll
            for (int h = 0; h < 12; h++) {
                const float e = __expf(p[h][reg] * SCALE);
                p[h][reg] = e;
                den += e;
            }
            const float inv = 1.0f / den;
#pragma unroll
            for (int h = 0; h < 12; h++) p[h][reg] *= inv;
        }

        __syncthreads();  // prior-iter PV reads of pP complete
        // --- P -> LDS (C-layout -> [h][n][m] row-major) ---
#pragma unroll
        for (int h = 0; h < 12; h++)
#pragma unroll
            for (int reg = 0; reg < 4; reg++)
                pP[(h * 16 + quad * 4 + reg) * 70 + wv * 16 + l16] = f2bf(p[h][reg]);
        __syncthreads();

        // --- PV: this wave's d16 chunk, all heads; V-frags from L2 ---
#pragma unroll
        for (int h = 0; h < 12; h++) {
            const short* vbase = vtb + ((b * HH + h) << 16) + ((wv * 16 + l16) << 10) + m0;
#pragma unroll
            for (int half = 0; half < 2; half++) {
                const bf16x8 pa = *reinterpret_cast<bf16x8*>(
                    &pP[(h * 16 + l16) * 70 + half * 32 + quad * 8]);
                const bf16x8 vf = *reinterpret_cast<const bf16x8*>(vbase + half * 32 + quad * 8);
                O[h] = MFMA16(pa, vf, O[h]);
            }
        }
    }

    // epilogue: O C-layout row=quad*4+reg (n), col=l16 (d within chunk)
#pragma unroll
    for (int h = 0; h < 12; h++) {
        const int col = h * 64 + wv * 16 + l16;
#pragma unroll
        for (int reg = 0; reg < 4; reg++) {
            const int n = n0 + quad * 4 + reg;
            attn_out[(size_t)((b << 10) + n) * 768 + col] = f2bf(O[h][reg]);
        }
    }
}

// ---------- launch ----------
extern "C" void kernel_launch(void* const* d_in, const int* in_sizes, int n_in,
                              void* d_out, int out_size, void* d_ws, size_t ws_size,
                              hipStream_t stream) {
    const float* x     = (const float*)d_in[0];
    const float* w_qkv = (const float*)d_in[1];
    const float* w_out = (const float*)d_in[2];
    const float* b_out = (const float*)d_in[3];
    float* out = (float*)d_out;

    short* xb   = (short*)d_ws;                 // [8192][768]
    short* wT1  = xb  + 8192 * 768;             // [2304][768]
    short* wT2  = wT1 + 2304 * 768;             // [768][768]
    short* qb   = wT2 + 768 * 768;              // [b][h][n][d]
    short* kb   = qb  + 96 * 65536;
    short* vtb  = kb  + 96 * 65536;             // [b][h][d][n]
    short* attn = vtb + 96 * 65536;             // [8192][768]

    cast_to_bf16<<<6144, 256, 0, stream>>>(x, xb, (8192 * 768) / 4);
    transpose_cast<<<(2304 * 768) / 256, 256, 0, stream>>>(w_qkv, wT1, 768, 2304);
    transpose_cast<<<(768 * 768) / 256, 256, 0, stream>>>(w_out, wT2, 768, 768);

    gemm128<0><<<dim3(2304 / 128, 8192 / 128), 256, 0, stream>>>(
        xb, wT1, 768, qb, kb, vtb, nullptr, nullptr);

    attn_fused2<<<512, 256, 0, stream>>>(qb, kb, vtb, attn);

    gemm128<1><<<dim3(768 / 128, 8192 / 128), 256, 0, stream>>>(
        attn, wT2, 768, nullptr, nullptr, nullptr, out, b_out);
}

// Round 5
// 333.324 us; speedup vs baseline: 1.1643x; 1.1643x over previous
//
#include <hip/hip_runtime.h>

// ---------- common types ----------
typedef float  f32x4  __attribute__((ext_vector_type(4)));
typedef short  bf16x8 __attribute__((ext_vector_type(8)));

#define MFMA16(a, b, c) __builtin_amdgcn_mfma_f32_16x16x32_bf16((a), (b), (c), 0, 0, 0)

__device__ __forceinline__ short f2bf(float f) {
    union { float f; unsigned u; } a; a.f = f;
    unsigned r = a.u + 0x7fffu + ((a.u >> 16) & 1u);  // RNE
    return (short)(r >> 16);
}
__device__ __forceinline__ float bf2f(unsigned short u) {
    union { unsigned u; float f; } a; a.u = ((unsigned)u) << 16; return a.f;
}

// sizes
#define Bb   8
#define Nn   1024
#define DIM  768
#define HH   12
#define HD   64
#define INNER 768
#define SCALE 0.125f

// ---------- prep kernels ----------
__global__ void cast_to_bf16(const float* __restrict__ in, short* __restrict__ out, int n4) {
    int i = blockIdx.x * 256 + threadIdx.x;
    if (i >= n4) return;
    float4 f = reinterpret_cast<const float4*>(in)[i];
    unsigned lo = (unsigned)(unsigned short)f2bf(f.x) | ((unsigned)(unsigned short)f2bf(f.y) << 16);
    unsigned hi = (unsigned)(unsigned short)f2bf(f.z) | ((unsigned)(unsigned short)f2bf(f.w) << 16);
    reinterpret_cast<uint2*>(out)[i] = make_uint2(lo, hi);
}

// wt[c][k] = w[k][c]; w is [rows=K][cols], wt is [cols][K]
__global__ void transpose_cast(const float* __restrict__ w, short* __restrict__ wt,
                               int rows, int cols) {
    int idx = blockIdx.x * 256 + threadIdx.x;
    if (idx >= rows * cols) return;
    int c = idx / rows;
    int k = idx - c * rows;
    wt[idx] = f2bf(w[k * cols + c]);
}

// ---------- GEMM: C[M,N] = A[M,K] @ Bt[N,K]^T ----------
template <int MODE>
__global__ __launch_bounds__(256, 2)
void gemm128(const short* __restrict__ A, const short* __restrict__ Bt, int K,
             short* __restrict__ qb, short* __restrict__ kb, short* __restrict__ vtb,
             float* __restrict__ outp, const float* __restrict__ bias) {
    __shared__ __align__(16) short As[128 * 40];
    __shared__ __align__(16) short Bs[128 * 40];

    const int tid  = threadIdx.x;
    const int lane = tid & 63, wv = tid >> 6;
    const int wrow = wv >> 1, wcol = wv & 1;
    const int quad = lane >> 4, l16 = lane & 15;
    const int m0 = blockIdx.y * 128, n0 = blockIdx.x * 128;

    const int srow = tid >> 1;
    const int soff = (tid & 1) * 16;

    f32x4 acc[4][4];
#pragma unroll
    for (int i = 0; i < 4; i++)
#pragma unroll
        for (int j = 0; j < 4; j++) acc[i][j] = (f32x4){0.f, 0.f, 0.f, 0.f};

    for (int kc = 0; kc < K; kc += 32) {
        const uint4 a0 = *reinterpret_cast<const uint4*>(A + (size_t)(m0 + srow) * K + kc + soff);
        const uint4 a1 = *reinterpret_cast<const uint4*>(A + (size_t)(m0 + srow) * K + kc + soff + 8);
        const uint4 b0 = *reinterpret_cast<const uint4*>(Bt + (size_t)(n0 + srow) * K + kc + soff);
        const uint4 b1 = *reinterpret_cast<const uint4*>(Bt + (size_t)(n0 + srow) * K + kc + soff + 8);
        __syncthreads();
        *reinterpret_cast<uint4*>(&As[srow * 40 + soff])     = a0;
        *reinterpret_cast<uint4*>(&As[srow * 40 + soff + 8]) = a1;
        *reinterpret_cast<uint4*>(&Bs[srow * 40 + soff])     = b0;
        *reinterpret_cast<uint4*>(&Bs[srow * 40 + soff + 8]) = b1;
        __syncthreads();

        bf16x8 af[4], bfr[4];
#pragma unroll
        for (int t = 0; t < 4; t++)
            af[t] = *reinterpret_cast<bf16x8*>(&As[(wrow * 64 + t * 16 + l16) * 40 + quad * 8]);
#pragma unroll
        for (int t = 0; t < 4; t++)
            bfr[t] = *reinterpret_cast<bf16x8*>(&Bs[(wcol * 64 + t * 16 + l16) * 40 + quad * 8]);
#pragma unroll
        for (int rt = 0; rt < 4; rt++)
#pragma unroll
            for (int ct = 0; ct < 4; ct++)
                acc[rt][ct] = MFMA16(af[rt], bfr[ct], acc[rt][ct]);
    }

    // epilogue: C/D layout col=lane&15, row=quad*4+reg
#pragma unroll
    for (int rt = 0; rt < 4; rt++) {
#pragma unroll
        for (int ct = 0; ct < 4; ct++) {
            const int c = n0 + wcol * 64 + ct * 16 + l16;
#pragma unroll
            for (int reg = 0; reg < 4; reg++) {
                const int r = m0 + wrow * 64 + rt * 16 + quad * 4 + reg;
                const float v = acc[rt][ct][reg];
                if (MODE == 0) {
                    const int b = r >> 10, n = r & 1023;
                    const int which = (c >= 1536) ? 2 : (c >= 768 ? 1 : 0);
                    const int cc = c - which * 768;
                    const int h = cc >> 6, d = cc & 63;
                    const int bh = b * HH + h;
                    const short bv = f2bf(v);
                    if (which == 0)      qb[(bh << 16) + (n << 6) + d] = bv;
                    else if (which == 1) kb[(bh << 16) + (n << 6) + d] = bv;
                    else                 vtb[(bh << 16) + (d << 10) + n] = bv;
                } else {
                    outp[(size_t)r * 768 + c] = v + bias[c];
                }
            }
        }
    }
}

// ---------- attention pass 1: barrier-free denominator ----------
// Wave tile 64n x 64m, NO LDS, NO barriers. Q/K MFMA fragments are read
// directly from global (L2-resident: per-b Q+K = 3 MB fits the XCD's 4 MB
// L2; b = bid&7 keeps each b's blocks on one XCD). den accumulates in
// registers across h (every head's S sits at the same (lane,reg) C-layout
// position). Output inv_den bf16 in raw C-layout tiles (round-3 interface).
__global__ __launch_bounds__(256, 2)
void attn_den3(const short* __restrict__ qb, const short* __restrict__ kb,
               short* __restrict__ invp) {
    const int tid = threadIdx.x, lane = tid & 63, wv = tid >> 6;
    const int quad = lane >> 4, l16 = lane & 15;
    const int b = blockIdx.x & 7;
    const int t = blockIdx.x >> 3;       // 0..63
    const int nb = t >> 3, mb = t & 7;   // 128x128 block tile
    const int n0 = (nb << 7) + ((wv >> 1) << 6);
    const int m0 = (mb << 7) + ((wv & 1) << 6);

    f32x4 den[4][4];
#pragma unroll
    for (int i = 0; i < 4; i++)
#pragma unroll
        for (int j = 0; j < 4; j++) den[i][j] = (f32x4){0.f, 0.f, 0.f, 0.f};
    const f32x4 z = (f32x4){0.f, 0.f, 0.f, 0.f};

    for (int h = 0; h < HH; h++) {
        const short* qp = qb + ((b * HH + h) << 16);
        const short* kp = kb + ((b * HH + h) << 16);
        bf16x8 aq[4][2], bk[4][2];
#pragma unroll
        for (int nt = 0; nt < 4; nt++) {
            const short* p = qp + ((n0 + nt * 16 + l16) << 6) + quad * 8;
            aq[nt][0] = *reinterpret_cast<const bf16x8*>(p);
            aq[nt][1] = *reinterpret_cast<const bf16x8*>(p + 32);
        }
#pragma unroll
        for (int mt = 0; mt < 4; mt++) {
            const short* p = kp + ((m0 + mt * 16 + l16) << 6) + quad * 8;
            bk[mt][0] = *reinterpret_cast<const bf16x8*>(p);
            bk[mt][1] = *reinterpret_cast<const bf16x8*>(p + 32);
        }
#pragma unroll
        for (int nt = 0; nt < 4; nt++)
#pragma unroll
            for (int mt = 0; mt < 4; mt++) {
                f32x4 s = MFMA16(aq[nt][0], bk[mt][0], z);
                s = MFMA16(aq[nt][1], bk[mt][1], s);
#pragma unroll
                for (int r = 0; r < 4; r++) den[nt][mt][r] += __expf(s[r] * SCALE);
            }
    }

#pragma unroll
    for (int nt = 0; nt < 4; nt++)
#pragma unroll
        for (int mt = 0; mt < 4; mt++) {
            const int ntg = (n0 >> 4) + nt;
            const int mtg = (m0 >> 4) + mt;
            ushort4 o;
            o.x = (unsigned short)f2bf(1.0f / den[nt][mt][0]);
            o.y = (unsigned short)f2bf(1.0f / den[nt][mt][1]);
            o.z = (unsigned short)f2bf(1.0f / den[nt][mt][2]);
            o.w = (unsigned short)f2bf(1.0f / den[nt][mt][3]);
            *reinterpret_cast<ushort4*>(&invp[(((b * 64 + ntg) * 64 + mtg) * 64 + lane) * 4]) = o;
        }
}

// ---------- attention pass 2: barrier-free recompute-S + PV ----------
// Wave = (b, h, n32). NO __syncthreads anywhere: K/V/invp fragments come
// straight from L2; P round-trips through a wave-PRIVATE LDS stash for the
// C->A layout transform (intra-wave RAW ordered by __threadfence_block —
// the pv2-proven pattern). O = 2x4 f32x4 = 32 VGPRs -> ~3 blocks/CU,
// grid 768 = exactly 3/CU, waves free-run with zero gang stalls.
__global__ __launch_bounds__(256, 3)
void attn_pv3(const short* __restrict__ qb, const short* __restrict__ kb,
              const short* __restrict__ vtb, const short* __restrict__ invp,
              short* __restrict__ attn_out) {
    __shared__ __align__(16) short Ps[4][2][16 * 40];  // [wave][nt][n16][m32]

    const int tid = threadIdx.x, lane = tid & 63, wv = tid >> 6;
    const int quad = lane >> 4, l16 = lane & 15;
    const int b = blockIdx.x & 7;
    const int r = blockIdx.x >> 3;       // 0..95
    const int h = r % 12;
    const int strip = r / 12;            // 0..7 (n128 strip)
    const int n0 = (strip << 7) + (wv << 5);
    const int bh = b * HH + h;

    // Q A-frags for 2 n16-tiles (persistent)
    bf16x8 aq[2][2];
#pragma unroll
    for (int nt = 0; nt < 2; nt++) {
        const short* qp = qb + (bh << 16) + ((n0 + nt * 16 + l16) << 6) + quad * 8;
        aq[nt][0] = *reinterpret_cast<const bf16x8*>(qp);
        aq[nt][1] = *reinterpret_cast<const bf16x8*>(qp + 32);
    }

    const f32x4 z = (f32x4){0.f, 0.f, 0.f, 0.f};
    f32x4 O[2][4];
#pragma unroll
    for (int nt = 0; nt < 2; nt++)
#pragma unroll
        for (int d = 0; d < 4; d++) O[nt][d] = z;

    for (int it = 0; it < 32; it++) {
        const int m0 = it << 5;

        // K frags for two m16 halves
        bf16x8 k[2][2];
#pragma unroll
        for (int mh = 0; mh < 2; mh++) {
            const short* kp = kb + (bh << 16) + ((m0 + mh * 16 + l16) << 6) + quad * 8;
            k[mh][0] = *reinterpret_cast<const bf16x8*>(kp);
            k[mh][1] = *reinterpret_cast<const bf16x8*>(kp + 32);
        }

        // S, P = exp(s*scale)*inv -> wave-private stash
#pragma unroll
        for (int nt = 0; nt < 2; nt++) {
            const int ntg = (n0 >> 4) + nt;
#pragma unroll
            for (int mh = 0; mh < 2; mh++) {
                f32x4 s = MFMA16(aq[nt][0], k[mh][0], z);
                s = MFMA16(aq[nt][1], k[mh][1], s);
                const int mtg = (m0 >> 4) + mh;
                const ushort4 iv = *reinterpret_cast<const ushort4*>(
                    &invp[(((b * 64 + ntg) * 64 + mtg) * 64 + lane) * 4]);
                Ps[wv][nt][(quad * 4 + 0) * 40 + mh * 16 + l16] = f2bf(__expf(s[0] * SCALE) * bf2f(iv.x));
                Ps[wv][nt][(quad * 4 + 1) * 40 + mh * 16 + l16] = f2bf(__expf(s[1] * SCALE) * bf2f(iv.y));
                Ps[wv][nt][(quad * 4 + 2) * 40 + mh * 16 + l16] = f2bf(__expf(s[2] * SCALE) * bf2f(iv.z));
                Ps[wv][nt][(quad * 4 + 3) * 40 + mh * 16 + l16] = f2bf(__expf(s[3] * SCALE) * bf2f(iv.w));
            }
        }
        __threadfence_block();  // intra-wave cross-lane RAW on Ps

        // PV: A-frag = P[n=l16][k=quad*8+j] over m32; V frags from L2
        bf16x8 pa[2];
#pragma unroll
        for (int nt = 0; nt < 2; nt++)
            pa[nt] = *reinterpret_cast<bf16x8*>(&Ps[wv][nt][l16 * 40 + quad * 8]);
#pragma unroll
        for (int dch = 0; dch < 4; dch++) {
            const bf16x8 vf = *reinterpret_cast<const bf16x8*>(
                vtb + (bh << 16) + ((dch * 16 + l16) << 10) + m0 + quad * 8);
#pragma unroll
            for (int nt = 0; nt < 2; nt++)
                O[nt][dch] = MFMA16(pa[nt], vf, O[nt][dch]);
        }
    }

    // epilogue: O C-layout row=quad*4+reg (n), col=l16 (d within chunk)
#pragma unroll
    for (int nt = 0; nt < 2; nt++)
#pragma unroll
        for (int dch = 0; dch < 4; dch++) {
            const int col = h * 64 + dch * 16 + l16;
#pragma unroll
            for (int reg = 0; reg < 4; reg++) {
                const int n = n0 + nt * 16 + quad * 4 + reg;
                attn_out[(size_t)((b << 10) + n) * 768 + col] = f2bf(O[nt][dch][reg]);
            }
        }
}

// ---------- launch ----------
extern "C" void kernel_launch(void* const* d_in, const int* in_sizes, int n_in,
                              void* d_out, int out_size, void* d_ws, size_t ws_size,
                              hipStream_t stream) {
    const float* x     = (const float*)d_in[0];
    const float* w_qkv = (const float*)d_in[1];
    const float* w_out = (const float*)d_in[2];
    const float* b_out = (const float*)d_in[3];
    float* out = (float*)d_out;

    short* xb   = (short*)d_ws;                 // [8192][768]
    short* wT1  = xb  + 8192 * 768;             // [2304][768]
    short* wT2  = wT1 + 2304 * 768;             // [768][768]
    short* qb   = wT2 + 768 * 768;              // [b][h][n][d]
    short* kb   = qb  + 96 * 65536;
    short* vtb  = kb  + 96 * 65536;             // [b][h][d][n]
    short* attn = vtb + 96 * 65536;             // [8192][768]
    short* invp = attn + 8192 * 768;            // [b][nt][mt][lane][4]

    cast_to_bf16<<<6144, 256, 0, stream>>>(x, xb, (8192 * 768) / 4);
    transpose_cast<<<(2304 * 768) / 256, 256, 0, stream>>>(w_qkv, wT1, 768, 2304);
    transpose_cast<<<(768 * 768) / 256, 256, 0, stream>>>(w_out, wT2, 768, 768);

    gemm128<0><<<dim3(2304 / 128, 8192 / 128), 256, 0, stream>>>(
        xb, wT1, 768, qb, kb, vtb, nullptr, nullptr);

    attn_den3<<<512, 256, 0, stream>>>(qb, kb, invp);
    attn_pv3<<<768, 256, 0, stream>>>(qb, kb, vtb, invp, attn);

    gemm128<1><<<dim3(768 / 128, 8192 / 128), 256, 0, stream>>>(
        attn, wT2, 768, nullptr, nullptr, nullptr, out, b_out);
}